// Round 19
// baseline (60.874 us; speedup 1.0000x reference)
//
#include <hip/hip_runtime.h>

#define NN   512
#define NN2  (NN * NN)
#define BB   64
#define ITERS 10
#define WM   40                    // landing-window dim & stride (|t|<=16 -> span<=36)
#define WWIN (WM * WM)             // 1600 floats
#define SBLK 16                    // splat blocks per batch (private windows)
#define NSPLAT (BB * SBLK)         // 1024 splat blocks
#define GPT  8                     // stream float4-groups per thread (deep MLP)
#define NSTREAM 1024               // stream blocks: 4.19M groups / (512*8)
#define NBLK (NSPLAT + NSTREAM)    // 2048
#define FTPB 512                   // fused kernel threads per block

// redistribution region: window (40) + 12 halo each side
#define RD   64
#define RST  69                    // LDS row stride (odd -> bank spread)
#define RTPB 1024                  // 64*16 float4-units = 1024 = 1/thread

typedef float floatx4 __attribute__((ext_vector_type(4)));   // NT-builtin-compatible

__device__ __forceinline__ float sigf(float x) { return 1.0f / (1.0f + __expf(-x)); }

__device__ __forceinline__ float maskf(float s, float t, float L) {
    if (fabsf(t) > 30.f || s < -30.f || s > L + 30.f) return 0.f;
    return sigf(3.f - fabsf(t)) * sigf(s) * sigf(L - s);
}

// base (pushed density without landing mass). s>=L => self-splat => rho.
__device__ __forceinline__ float base_elem2(float o, float s, float t, float L) {
    float m = maskf(s, t, L);
    return (s >= L) ? o : o * (1.f - m);
}

// ---------------- Pass 1 (fused): splat + stream, mod-2 interleaved roles ---------
// bid&1 -> splat block q=bid>>1 (0..1023); else stream block q (0..1023).
__global__ void __launch_bounds__(FTPB) fused_kernel(
        const float* __restrict__ occ,
        const float* __restrict__ as_,
        const float* __restrict__ ae_,
        float* __restrict__ ws,
        float* __restrict__ out) {
    __shared__ float win[WWIN];
    const int bid = blockIdx.x;
    const int tid = threadIdx.x;
    const int q   = bid >> 1;
    const int r   = bid & 1;

    if (r == 1) {
        // ---------------- splat block q in 0..1023 (r17-identical) ----------------
        const int b  = q >> 4;
        const int qb = q & (SBLK - 1);

        const float p0x = as_[2 * b], p0y = as_[2 * b + 1];
        const float p1x = ae_[2 * b], p1y = ae_[2 * b + 1];
        const float dx = p1x - p0x, dy = p1y - p0y;
        const float L  = sqrtf(dx * dx + dy * dy + 1e-12f);
        const float u0 = dx / L, u1 = dy / L;
        const float au0 = fabsf(u0), au1 = fabsf(u1);
        const int wx0 = (int)floorf(p1x - 16.f * au1) - 2;
        const int wy0 = (int)floorf(p1y - 16.f * au0) - 2;
        const bool degen = (dx == 0.f && dy == 0.f);

        for (int k = tid; k < WWIN; k += FTPB) win[k] = 0.f;
        __syncthreads();

        if (!degen) {
            const float* ob = occ + ((size_t)b << 18);
            const bool caseA = (au0 >= au1);   // lines = rows; else columns
            const int wave = tid >> 6;          // 0..7
            const int lane = tid & 63;

            #pragma unroll
            for (int k2 = 0; k2 < 4; ++k2) {
                const int a = qb + 16 * (wave + 8 * k2);   // line index 0..511
                const float fa = (float)a;
                float lo, hi;
                bool skip = false;
                if (caseA) {
                    // line = row a: t(j) = -rx*u1 + (j-p0y)*u0  (|u0| >= 0.707)
                    float rxl = fa - p0x;
                    float c1 = p0y + (rxl * u1 - 16.f) / u0;
                    float c2 = p0y + (rxl * u1 + 16.f) / u0;
                    lo = fminf(c1, c2); hi = fmaxf(c1, c2);
                    if (au1 > 1e-6f) {
                        float c3 = p0y + (-16.f - rxl * u0) / u1;
                        float c4 = p0y + (L     - rxl * u0) / u1;
                        lo = fmaxf(lo, fminf(c3, c4));
                        hi = fminf(hi, fmaxf(c3, c4));
                    } else {
                        float sc = rxl * u0;
                        skip = (sc < -16.5f) || (sc > L + 0.5f);
                    }
                } else {
                    // line = column a: t(i) = -(i-p0x)*u1 + ry*u0  (|u1| >= 0.707)
                    float ryl = fa - p0y;
                    float c1 = p0x + (ryl * u0 - 16.f) / u1;
                    float c2 = p0x + (ryl * u0 + 16.f) / u1;
                    lo = fminf(c1, c2); hi = fmaxf(c1, c2);
                    if (au0 > 1e-6f) {
                        float c3 = p0x + (-16.f - ryl * u1) / u0;
                        float c4 = p0x + (L     - ryl * u1) / u0;
                        lo = fmaxf(lo, fminf(c3, c4));
                        hi = fminf(hi, fmaxf(c3, c4));
                    } else {
                        float sc = ryl * u1;
                        skip = (sc < -16.5f) || (sc > L + 0.5f);
                    }
                }
                if (skip) continue;
                int clo = max((int)floorf(lo) - 1, 0);
                int chi = min((int)ceilf(hi) + 1, NN - 1);

                for (int c = clo + lane; c <= chi; c += 64) {
                    int i = caseA ? a : c;
                    int j = caseA ? c : a;
                    float rx = (float)i - p0x, ry = (float)j - p0y;
                    float s = rx * u0 + ry * u1;
                    float t = -rx * u1 + ry * u0;
                    if (fabsf(t) > 16.f || s < -16.f || s >= L) continue;
                    float rho = ob[i * NN + j];
                    float mask  = sigf(3.f - fabsf(t)) * sigf(s) * sigf(L - s);
                    float moved = rho * mask;
                    if (moved <= 1e-10f) continue;
                    float xf = p1x - t * u1;             // landing depends only on t
                    float yf = p1y + t * u0;
                    float x0 = floorf(xf), y0 = floorf(yf);
                    float fx = xf - x0, fy = yf - y0;
                    int base = ((int)x0 - wx0) * WM + ((int)y0 - wy0);
                    atomicAdd(&win[base],          (1.f - fx) * (1.f - fy) * moved);
                    atomicAdd(&win[base + 1],      (1.f - fx) * fy * moved);
                    atomicAdd(&win[base + WM],     fx * (1.f - fy) * moved);
                    atomicAdd(&win[base + WM + 1], fx * fy * moved);
                }
            }
        }
        __syncthreads();
        float* wsb = ws + (size_t)q * WWIN;   // private window, plain stores
        for (int k = tid; k < WWIN; k += FTPB) wsb[k] = win[k];
    } else {
        // ------------- stream block: 8 batched NT loads per thread (deep MLP) ----
        const int sb = q;                        // 0..1023
        const int b  = sb >> 4;                  // 16 stream blocks per batch

        const float p0x = as_[2 * b], p0y = as_[2 * b + 1];
        const float p1x = ae_[2 * b], p1y = ae_[2 * b + 1];
        const float dx = p1x - p0x, dy = p1y - p0y;
        const float L  = sqrtf(dx * dx + dy * dy + 1e-12f);
        const float u0 = dx / L, u1 = dy / L;
        const bool degen = (dx == 0.f && dy == 0.f);

        const float* ob   = occ + ((size_t)b << 18);
        float*       outb = out + ((size_t)b << 18);
        const int rem0 = (sb & 15) * (FTPB * GPT) + tid;   // group id, +k*FTPB

        // batch all 8 loads first: 8 outstanding vmem ops (128 B/thread in flight)
        floatx4 o0, o1, o2, o3, o4, o5, o6, o7;
        {
            int rem, i, j0;
            rem = rem0;             i = rem >> 7; j0 = (rem & 127) << 2;
            o0 = __builtin_nontemporal_load(reinterpret_cast<const floatx4*>(ob + i * NN + j0));
            rem = rem0 + FTPB;      i = rem >> 7; j0 = (rem & 127) << 2;
            o1 = __builtin_nontemporal_load(reinterpret_cast<const floatx4*>(ob + i * NN + j0));
            rem = rem0 + 2 * FTPB;  i = rem >> 7; j0 = (rem & 127) << 2;
            o2 = __builtin_nontemporal_load(reinterpret_cast<const floatx4*>(ob + i * NN + j0));
            rem = rem0 + 3 * FTPB;  i = rem >> 7; j0 = (rem & 127) << 2;
            o3 = __builtin_nontemporal_load(reinterpret_cast<const floatx4*>(ob + i * NN + j0));
            rem = rem0 + 4 * FTPB;  i = rem >> 7; j0 = (rem & 127) << 2;
            o4 = __builtin_nontemporal_load(reinterpret_cast<const floatx4*>(ob + i * NN + j0));
            rem = rem0 + 5 * FTPB;  i = rem >> 7; j0 = (rem & 127) << 2;
            o5 = __builtin_nontemporal_load(reinterpret_cast<const floatx4*>(ob + i * NN + j0));
            rem = rem0 + 6 * FTPB;  i = rem >> 7; j0 = (rem & 127) << 2;
            o6 = __builtin_nontemporal_load(reinterpret_cast<const floatx4*>(ob + i * NN + j0));
            rem = rem0 + 7 * FTPB;  i = rem >> 7; j0 = (rem & 127) << 2;
            o7 = __builtin_nontemporal_load(reinterpret_cast<const floatx4*>(ob + i * NN + j0));
        }

        #define STREAM_ONE(KK, OV)                                               \
        {                                                                        \
            int rem = rem0 + (KK) * FTPB;                                        \
            int i   = rem >> 7;                                                  \
            int j0  = (rem & 127) << 2;                                          \
            floatx4 v;                                                           \
            float rx = (float)i - p0x;                                           \
            float ry = (float)j0 - p0y;                                          \
            float s0 = rx * u0 + ry * u1;                                        \
            float t0 = -rx * u1 + ry * u0;                                       \
            float s3 = s0 + 3.f * u1;                                            \
            float t3 = t0 + 3.f * u0;                                            \
            float tA = fminf(t0, t3), tB = fmaxf(t0, t3);                        \
            float sA = fminf(s0, s3), sB = fmaxf(s0, s3);                        \
            if (degen || tA > 30.f || tB < -30.f || sB < -30.f || sA >= L) {     \
                v = OV;                                                          \
            } else {                                                             \
                v.x = base_elem2(OV.x, s0,            t0,            L);         \
                v.y = base_elem2(OV.y, s0 + u1,       t0 + u0,       L);         \
                v.z = base_elem2(OV.z, s0 + 2.f * u1, t0 + 2.f * u0, L);         \
                v.w = base_elem2(OV.w, s3,            t3,            L);         \
            }                                                                    \
            __builtin_nontemporal_store(v,                                       \
                reinterpret_cast<floatx4*>(outb + i * NN + j0));                 \
        }
        STREAM_ONE(0, o0)
        STREAM_ONE(1, o1)
        STREAM_ONE(2, o2)
        STREAM_ONE(3, o3)
        STREAM_ONE(4, o4)
        STREAM_ONE(5, o5)
        STREAM_ONE(6, o6)
        STREAM_ONE(7, o7)
        #undef STREAM_ONE
    }
}

// ---------------- Pass 2: per-batch region redistribution (1 unit/thread) --------
__global__ void __launch_bounds__(RTPB) redist_kernel(
        const float* __restrict__ ws,
        const float* __restrict__ as_,
        const float* __restrict__ ae_,
        float* __restrict__ out) {
    __shared__ float smem[RD * RST];
    __shared__ float winsum[WWIN];
    const int b   = blockIdx.x;
    const int tid = threadIdx.x;

    const float p0x = as_[2 * b], p0y = as_[2 * b + 1];
    const float p1x = ae_[2 * b], p1y = ae_[2 * b + 1];
    const float dx = p1x - p0x, dy = p1y - p0y;
    const float L  = sqrtf(dx * dx + dy * dy + 1e-12f);
    const float pu0 = dx / L, pu1 = dy / L;
    const float au0 = fabsf(pu0), au1 = fabsf(pu1);
    const int wx0 = (int)floorf(p1x - 16.f * au1) - 2;   // identical expr to splat
    const int wy0 = (int)floorf(p1y - 16.f * au0) - 2;
    const int rx0 = wx0 - 12;
    const int ry0 = wy0 - 12;
    const float dn  = sqrtf(dx * dx + dy * dy);
    const bool active = dn > 1e-6f;
    const float rdn = fmaxf(dn, 1e-6f);
    const float ru0 = dx / rdn, ru1 = dy / rdn;
    const float s0f = floorf(ru0), s1f = floorf(ru1);
    const float f0 = ru0 - s0f, f1 = ru1 - s1f;
    const int oi = -(int)s0f;
    const int oj = -(int)s1f;
    const float wA0 = 1.f - f0, wB0 = f0;
    const float wA1 = 1.f - f1, wB1 = f1;

    const float* wsb  = ws  + (size_t)b * (SBLK * WWIN);
    float*       outb = out + ((size_t)b << 18);

    // pre-sum the SBLK private windows (coalesced) into LDS
    for (int k = tid; k < WWIN; k += RTPB) {
        float s = 0.f;
        #pragma unroll
        for (int w = 0; w < SBLK; ++w) s += wsb[w * WWIN + k];
        winsum[k] = s;
    }
    __syncthreads();

    // one float4-unit per thread: li 0..63, lj 0..60
    const int li = tid >> 4;
    const int lj = (tid & 15) << 2;
    const int gi = rx0 + li;
    const int gj = ry0 + lj;
    const bool rok = (gi >= 0) && (gi < NN);
    float4 vm, r = make_float4(0.f, 0.f, 0.f, 0.f);
    vm.x = (rok && (unsigned)(gj + 0) < NN) ? 1.f : 0.f;
    vm.y = (rok && (unsigned)(gj + 1) < NN) ? 1.f : 0.f;
    vm.z = (rok && (unsigned)(gj + 2) < NN) ? 1.f : 0.f;
    vm.w = (rok && (unsigned)(gj + 3) < NN) ? 1.f : 0.f;
    if (rok) {
        const float* orow = outb + gi * NN;
        int cx = li - 12;
        bool cxok = (unsigned)cx < (unsigned)WM;
        float* rp = (float*)&r;
        const float* vmp = (const float*)&vm;
        #pragma unroll
        for (int e = 0; e < 4; ++e) {
            if (vmp[e] > 0.f) {
                float t = orow[gj + e];
                int cy = lj + e - 12;
                if (cxok && (unsigned)cy < (unsigned)WM) t += winsum[cx * WM + cy];
                rp[e] = t;
            }
        }
    }

    const int rA  = min(max(li + oi, 0), RD - 1);
    const int dB  = (min(max(li + oi - 1, 0), RD - 1) - rA) * RST;
    const int wa  = li * RST + lj;
    const int aA0 = rA * RST + max(lj + oj - 1, 0);
    const int aA1 = rA * RST + (lj + oj + 0);
    const int aA2 = rA * RST + (lj + oj + 1);
    const int aA3 = rA * RST + (lj + oj + 2);
    const int aA4 = rA * RST + min(lj + oj + 3, RD - 1);

    if (active) {
        for (int it = 0; it < ITERS; ++it) {
            smem[wa + 0] = fmaxf(r.x - 1.f, 0.f);
            smem[wa + 1] = fmaxf(r.y - 1.f, 0.f);
            smem[wa + 2] = fmaxf(r.z - 1.f, 0.f);
            smem[wa + 3] = fmaxf(r.w - 1.f, 0.f);
            __syncthreads();
            float eA0 = smem[aA0], eA1 = smem[aA1], eA2 = smem[aA2];
            float eA3 = smem[aA3], eA4 = smem[aA4];
            float eB0 = smem[aA0 + dB], eB1 = smem[aA1 + dB];
            float eB2 = smem[aA2 + dB], eB3 = smem[aA3 + dB];
            float eB4 = smem[aA4 + dB];
            float g;
            g = wA0 * (wA1 * eA1 + wB1 * eA0) + wB0 * (wA1 * eB1 + wB1 * eB0);
            r.x = (fminf(r.x, 1.f) + g) * vm.x;
            g = wA0 * (wA1 * eA2 + wB1 * eA1) + wB0 * (wA1 * eB2 + wB1 * eB1);
            r.y = (fminf(r.y, 1.f) + g) * vm.y;
            g = wA0 * (wA1 * eA3 + wB1 * eA2) + wB0 * (wA1 * eB3 + wB1 * eB2);
            r.z = (fminf(r.z, 1.f) + g) * vm.z;
            g = wA0 * (wA1 * eA4 + wB1 * eA3) + wB0 * (wA1 * eB4 + wB1 * eB3);
            r.w = (fminf(r.w, 1.f) + g) * vm.w;
            __syncthreads();
        }
    }

    if (rok) {
        float* orow = outb + gi * NN;
        if (vm.x > 0.f) orow[gj + 0] = r.x;
        if (vm.y > 0.f) orow[gj + 1] = r.y;
        if (vm.z > 0.f) orow[gj + 2] = r.z;
        if (vm.w > 0.f) orow[gj + 3] = r.w;
    }
}

extern "C" void kernel_launch(void* const* d_in, const int* in_sizes, int n_in,
                              void* d_out, int out_size, void* d_ws, size_t ws_size,
                              hipStream_t stream) {
    const float* occ = (const float*)d_in[0];
    const float* as_ = (const float*)d_in[1];
    const float* ae_ = (const float*)d_in[2];
    float* out = (float*)d_out;
    float* ws  = (float*)d_ws;

    fused_kernel<<<NBLK, FTPB, 0, stream>>>(occ, as_, ae_, ws, out);

    redist_kernel<<<BB, RTPB, 0, stream>>>(ws, as_, ae_, out);
}

// Round 23
// 48.456 us; speedup vs baseline: 1.2563x; 1.2563x over previous
//
#include <hip/hip_runtime.h>

#define NN   512
#define NN2  (NN * NN)
#define BB   64
#define ITERS 10
#define WM   40                    // landing-window dim & stride (|t|<=16 -> span<=36)
#define WWIN (WM * WM)             // 1600 floats
#define SBLK 16                    // splat blocks per batch (private windows)
#define NSPLAT (BB * SBLK)         // 1024 splat blocks
#define GPT  4                     // stream float4-groups per thread (ILP)
#define NSTREAM 2048               // stream blocks: 4.19M groups / (512*4)
#define NBLK (NSPLAT + NSTREAM)    // 3072
#define FTPB 512                   // fused kernel threads per block

// redistribution region: window (40) + 12 halo each side
#define RD   64
#define RST  69                    // LDS row stride (odd -> bank spread)
#define RTPB 1024                  // 64*16 float4-units = 1024 = 1/thread

typedef float floatx4 __attribute__((ext_vector_type(4)));   // NT-builtin-compatible

__device__ __forceinline__ float sigf(float x) { return 1.0f / (1.0f + __expf(-x)); }

__device__ __forceinline__ float maskf(float s, float t, float L) {
    if (fabsf(t) > 30.f || s < -30.f || s > L + 30.f) return 0.f;
    return sigf(3.f - fabsf(t)) * sigf(s) * sigf(L - s);
}

// base (pushed density without landing mass). s>=L => self-splat => rho.
__device__ __forceinline__ float base_elem2(float o, float s, float t, float L) {
    float m = maskf(s, t, L);
    return (s >= L) ? o : o * (1.f - m);
}

// ---------------- Pass 1 (fused): splat + stream, mod-3 interleaved roles ---------
// bid%3==2 -> splat block q=bid/3 (0..1023); else stream block 2q+r (0..2047).
// PLAIN loads (occ stays L3-resident across replays) + NT stores (out bypasses,
// leaving L3 capacity for occ).
__global__ void __launch_bounds__(FTPB) fused_kernel(
        const float* __restrict__ occ,
        const float* __restrict__ as_,
        const float* __restrict__ ae_,
        float* __restrict__ ws,
        float* __restrict__ out) {
    __shared__ float win[WWIN];
    const int bid = blockIdx.x;
    const int tid = threadIdx.x;
    const int q   = bid / 3;
    const int r   = bid - 3 * q;

    if (r == 2) {
        // ---------------- splat block q in 0..1023 ----------------
        const int b  = q >> 4;
        const int qb = q & (SBLK - 1);

        const float p0x = as_[2 * b], p0y = as_[2 * b + 1];
        const float p1x = ae_[2 * b], p1y = ae_[2 * b + 1];
        const float dx = p1x - p0x, dy = p1y - p0y;
        const float L  = sqrtf(dx * dx + dy * dy + 1e-12f);
        const float u0 = dx / L, u1 = dy / L;
        const float au0 = fabsf(u0), au1 = fabsf(u1);
        const int wx0 = (int)floorf(p1x - 16.f * au1) - 2;
        const int wy0 = (int)floorf(p1y - 16.f * au0) - 2;
        const bool degen = (dx == 0.f && dy == 0.f);

        for (int k = tid; k < WWIN; k += FTPB) win[k] = 0.f;
        __syncthreads();

        if (!degen) {
            const float* ob = occ + ((size_t)b << 18);
            const bool caseA = (au0 >= au1);   // lines = rows; else columns
            const int wave = tid >> 6;
            const int lane = tid & 63;

            #pragma unroll
            for (int k2 = 0; k2 < 4; ++k2) {
                const int a = qb + 16 * (wave + 8 * k2);   // line index 0..511
                const float fa = (float)a;
                float lo, hi;
                bool skip = false;
                if (caseA) {
                    // line = row a: t(j) = -rx*u1 + (j-p0y)*u0  (|u0| >= 0.707)
                    float rxl = fa - p0x;
                    float c1 = p0y + (rxl * u1 - 16.f) / u0;
                    float c2 = p0y + (rxl * u1 + 16.f) / u0;
                    lo = fminf(c1, c2); hi = fmaxf(c1, c2);
                    if (au1 > 1e-6f) {
                        float c3 = p0y + (-16.f - rxl * u0) / u1;
                        float c4 = p0y + (L     - rxl * u0) / u1;
                        lo = fmaxf(lo, fminf(c3, c4));
                        hi = fminf(hi, fmaxf(c3, c4));
                    } else {
                        float sc = rxl * u0;
                        skip = (sc < -16.5f) || (sc > L + 0.5f);
                    }
                } else {
                    // line = column a: t(i) = -(i-p0x)*u1 + ry*u0  (|u1| >= 0.707)
                    float ryl = fa - p0y;
                    float c1 = p0x + (ryl * u0 - 16.f) / u1;
                    float c2 = p0x + (ryl * u0 + 16.f) / u1;
                    lo = fminf(c1, c2); hi = fmaxf(c1, c2);
                    if (au0 > 1e-6f) {
                        float c3 = p0x + (-16.f - ryl * u1) / u0;
                        float c4 = p0x + (L     - ryl * u1) / u0;
                        lo = fmaxf(lo, fminf(c3, c4));
                        hi = fminf(hi, fmaxf(c3, c4));
                    } else {
                        float sc = ryl * u1;
                        skip = (sc < -16.5f) || (sc > L + 0.5f);
                    }
                }
                if (skip) continue;
                int clo = max((int)floorf(lo) - 1, 0);
                int chi = min((int)ceilf(hi) + 1, NN - 1);

                for (int c = clo + lane; c <= chi; c += 64) {
                    int i = caseA ? a : c;
                    int j = caseA ? c : a;
                    float rx = (float)i - p0x, ry = (float)j - p0y;
                    float s = rx * u0 + ry * u1;
                    float t = -rx * u1 + ry * u0;
                    if (fabsf(t) > 16.f || s < -16.f || s >= L) continue;
                    float rho = ob[i * NN + j];
                    float mask  = sigf(3.f - fabsf(t)) * sigf(s) * sigf(L - s);
                    float moved = rho * mask;
                    if (moved <= 1e-10f) continue;
                    float xf = p1x - t * u1;             // landing depends only on t
                    float yf = p1y + t * u0;
                    float x0 = floorf(xf), y0 = floorf(yf);
                    float fx = xf - x0, fy = yf - y0;
                    int base = ((int)x0 - wx0) * WM + ((int)y0 - wy0);
                    atomicAdd(&win[base],          (1.f - fx) * (1.f - fy) * moved);
                    atomicAdd(&win[base + 1],      (1.f - fx) * fy * moved);
                    atomicAdd(&win[base + WM],     fx * (1.f - fy) * moved);
                    atomicAdd(&win[base + WM + 1], fx * fy * moved);
                }
            }
        }
        __syncthreads();
        float* wsb = ws + (size_t)q * WWIN;   // private window, plain stores
        for (int k = tid; k < WWIN; k += FTPB) wsb[k] = win[k];
    } else {
        // ------------- stream block: batched PLAIN loads, NT stores --------------
        const int sb = 2 * q + r;                // 0..2047
        const int b  = sb >> 5;                  // 32 stream blocks per batch

        const float p0x = as_[2 * b], p0y = as_[2 * b + 1];
        const float p1x = ae_[2 * b], p1y = ae_[2 * b + 1];
        const float dx = p1x - p0x, dy = p1y - p0y;
        const float L  = sqrtf(dx * dx + dy * dy + 1e-12f);
        const float u0 = dx / L, u1 = dy / L;
        const bool degen = (dx == 0.f && dy == 0.f);

        const float* ob   = occ + ((size_t)b << 18);
        float*       outb = out + ((size_t)b << 18);
        const int rem0 = (sb & 31) * (FTPB * GPT) + tid;   // group id, +k*FTPB

        // batch all 4 loads first: 4 outstanding vmem ops (plain -> L3-cacheable)
        floatx4 o0, o1, o2, o3;
        {
            int rem, i, j0;
            rem = rem0;             i = rem >> 7; j0 = (rem & 127) << 2;
            o0 = *reinterpret_cast<const floatx4*>(ob + i * NN + j0);
            rem = rem0 + FTPB;      i = rem >> 7; j0 = (rem & 127) << 2;
            o1 = *reinterpret_cast<const floatx4*>(ob + i * NN + j0);
            rem = rem0 + 2 * FTPB;  i = rem >> 7; j0 = (rem & 127) << 2;
            o2 = *reinterpret_cast<const floatx4*>(ob + i * NN + j0);
            rem = rem0 + 3 * FTPB;  i = rem >> 7; j0 = (rem & 127) << 2;
            o3 = *reinterpret_cast<const floatx4*>(ob + i * NN + j0);
        }

        #define STREAM_ONE(KK, OV)                                               \
        {                                                                        \
            int rem = rem0 + (KK) * FTPB;                                        \
            int i   = rem >> 7;                                                  \
            int j0  = (rem & 127) << 2;                                          \
            floatx4 v;                                                           \
            float rx = (float)i - p0x;                                           \
            float ry = (float)j0 - p0y;                                          \
            float s0 = rx * u0 + ry * u1;                                        \
            float t0 = -rx * u1 + ry * u0;                                       \
            float s3 = s0 + 3.f * u1;                                            \
            float t3 = t0 + 3.f * u0;                                            \
            float tA = fminf(t0, t3), tB = fmaxf(t0, t3);                        \
            float sA = fminf(s0, s3), sB = fmaxf(s0, s3);                        \
            if (degen || tA > 30.f || tB < -30.f || sB < -30.f || sA >= L) {     \
                v = OV;                                                          \
            } else {                                                             \
                v.x = base_elem2(OV.x, s0,            t0,            L);         \
                v.y = base_elem2(OV.y, s0 + u1,       t0 + u0,       L);         \
                v.z = base_elem2(OV.z, s0 + 2.f * u1, t0 + 2.f * u0, L);         \
                v.w = base_elem2(OV.w, s3,            t3,            L);         \
            }                                                                    \
            __builtin_nontemporal_store(v,                                       \
                reinterpret_cast<floatx4*>(outb + i * NN + j0));                 \
        }
        STREAM_ONE(0, o0)
        STREAM_ONE(1, o1)
        STREAM_ONE(2, o2)
        STREAM_ONE(3, o3)
        #undef STREAM_ONE
    }
}

// ---------------- Pass 2: per-batch region redistribution (1 unit/thread) --------
__global__ void __launch_bounds__(RTPB) redist_kernel(
        const float* __restrict__ ws,
        const float* __restrict__ as_,
        const float* __restrict__ ae_,
        float* __restrict__ out) {
    __shared__ float smem[RD * RST];
    __shared__ float winsum[WWIN];
    const int b   = blockIdx.x;
    const int tid = threadIdx.x;

    const float p0x = as_[2 * b], p0y = as_[2 * b + 1];
    const float p1x = ae_[2 * b], p1y = ae_[2 * b + 1];
    const float dx = p1x - p0x, dy = p1y - p0y;
    const float L  = sqrtf(dx * dx + dy * dy + 1e-12f);
    const float pu0 = dx / L, pu1 = dy / L;
    const float au0 = fabsf(pu0), au1 = fabsf(pu1);
    const int wx0 = (int)floorf(p1x - 16.f * au1) - 2;   // identical expr to splat
    const int wy0 = (int)floorf(p1y - 16.f * au0) - 2;
    const int rx0 = wx0 - 12;
    const int ry0 = wy0 - 12;
    const float dn  = sqrtf(dx * dx + dy * dy);
    const bool active = dn > 1e-6f;
    const float rdn = fmaxf(dn, 1e-6f);
    const float ru0 = dx / rdn, ru1 = dy / rdn;
    const float s0f = floorf(ru0), s1f = floorf(ru1);
    const float f0 = ru0 - s0f, f1 = ru1 - s1f;
    const int oi = -(int)s0f;
    const int oj = -(int)s1f;
    const float wA0 = 1.f - f0, wB0 = f0;
    const float wA1 = 1.f - f1, wB1 = f1;

    const float* wsb  = ws  + (size_t)b * (SBLK * WWIN);
    float*       outb = out + ((size_t)b << 18);

    // pre-sum the SBLK private windows (coalesced) into LDS
    for (int k = tid; k < WWIN; k += RTPB) {
        float s = 0.f;
        #pragma unroll
        for (int w = 0; w < SBLK; ++w) s += wsb[w * WWIN + k];
        winsum[k] = s;
    }
    __syncthreads();

    // one float4-unit per thread: li 0..63, lj 0..60
    const int li = tid >> 4;
    const int lj = (tid & 15) << 2;
    const int gi = rx0 + li;
    const int gj = ry0 + lj;
    const bool rok = (gi >= 0) && (gi < NN);
    float4 vm, r = make_float4(0.f, 0.f, 0.f, 0.f);
    vm.x = (rok && (unsigned)(gj + 0) < NN) ? 1.f : 0.f;
    vm.y = (rok && (unsigned)(gj + 1) < NN) ? 1.f : 0.f;
    vm.z = (rok && (unsigned)(gj + 2) < NN) ? 1.f : 0.f;
    vm.w = (rok && (unsigned)(gj + 3) < NN) ? 1.f : 0.f;
    if (rok) {
        const float* orow = outb + gi * NN;
        int cx = li - 12;
        bool cxok = (unsigned)cx < (unsigned)WM;
        float* rp = (float*)&r;
        const float* vmp = (const float*)&vm;
        #pragma unroll
        for (int e = 0; e < 4; ++e) {
            if (vmp[e] > 0.f) {
                float t = orow[gj + e];
                int cy = lj + e - 12;
                if (cxok && (unsigned)cy < (unsigned)WM) t += winsum[cx * WM + cy];
                rp[e] = t;
            }
        }
    }

    const int rA  = min(max(li + oi, 0), RD - 1);
    const int dB  = (min(max(li + oi - 1, 0), RD - 1) - rA) * RST;
    const int wa  = li * RST + lj;
    const int aA0 = rA * RST + max(lj + oj - 1, 0);
    const int aA1 = rA * RST + (lj + oj + 0);
    const int aA2 = rA * RST + (lj + oj + 1);
    const int aA3 = rA * RST + (lj + oj + 2);
    const int aA4 = rA * RST + min(lj + oj + 3, RD - 1);

    if (active) {
        for (int it = 0; it < ITERS; ++it) {
            smem[wa + 0] = fmaxf(r.x - 1.f, 0.f);
            smem[wa + 1] = fmaxf(r.y - 1.f, 0.f);
            smem[wa + 2] = fmaxf(r.z - 1.f, 0.f);
            smem[wa + 3] = fmaxf(r.w - 1.f, 0.f);
            __syncthreads();
            float eA0 = smem[aA0], eA1 = smem[aA1], eA2 = smem[aA2];
            float eA3 = smem[aA3], eA4 = smem[aA4];
            float eB0 = smem[aA0 + dB], eB1 = smem[aA1 + dB];
            float eB2 = smem[aA2 + dB], eB3 = smem[aA3 + dB];
            float eB4 = smem[aA4 + dB];
            float g;
            g = wA0 * (wA1 * eA1 + wB1 * eA0) + wB0 * (wA1 * eB1 + wB1 * eB0);
            r.x = (fminf(r.x, 1.f) + g) * vm.x;
            g = wA0 * (wA1 * eA2 + wB1 * eA1) + wB0 * (wA1 * eB2 + wB1 * eB1);
            r.y = (fminf(r.y, 1.f) + g) * vm.y;
            g = wA0 * (wA1 * eA3 + wB1 * eA2) + wB0 * (wA1 * eB3 + wB1 * eB2);
            r.z = (fminf(r.z, 1.f) + g) * vm.z;
            g = wA0 * (wA1 * eA4 + wB1 * eA3) + wB0 * (wA1 * eB4 + wB1 * eB3);
            r.w = (fminf(r.w, 1.f) + g) * vm.w;
            __syncthreads();
        }
    }

    if (rok) {
        float* orow = outb + gi * NN;
        if (vm.x > 0.f) orow[gj + 0] = r.x;
        if (vm.y > 0.f) orow[gj + 1] = r.y;
        if (vm.z > 0.f) orow[gj + 2] = r.z;
        if (vm.w > 0.f) orow[gj + 3] = r.w;
    }
}

extern "C" void kernel_launch(void* const* d_in, const int* in_sizes, int n_in,
                              void* d_out, int out_size, void* d_ws, size_t ws_size,
                              hipStream_t stream) {
    const float* occ = (const float*)d_in[0];
    const float* as_ = (const float*)d_in[1];
    const float* ae_ = (const float*)d_in[2];
    float* out = (float*)d_out;
    float* ws  = (float*)d_ws;

    fused_kernel<<<NBLK, FTPB, 0, stream>>>(occ, as_, ae_, ws, out);

    redist_kernel<<<BB, RTPB, 0, stream>>>(ws, as_, ae_, out);
}